// Round 1
// baseline (2983.104 us; speedup 1.0000x reference)
//
#include <hip/hip_runtime.h>

#define D 128  // D_IN == D_OUT == 128

// ---------------------------------------------------------------------------
// Stage 1: h[n][o] = sum_k x[n][k] * W[o][k]   (x:[N,128], W:[128,128] row-major)
// Block = 128 threads (2 waves). W staged in LDS with stride 132 floats so
// per-thread float4 row reads are bank-conflict-free. Each pass: 4 rows of x
// broadcast from LDS, each thread owns one output column.
// LDS: 128*132*4 = 66 KiB + 2 KiB xs -> 2 blocks/CU.
// ---------------------------------------------------------------------------
__global__ __launch_bounds__(128) void gemm_xWt(const float* __restrict__ x,
                                                const float* __restrict__ W,
                                                float* __restrict__ h,
                                                int N) {
    constexpr int WS = 132;  // padded stride in floats (33 mod 8 == 1 -> conflict-free b128)
    __shared__ float Ws[128 * WS];
    __shared__ float4 xs4[4][32];
    const int tid = threadIdx.x;

    // Cooperative load of W into padded LDS (4096 float4s / 128 threads)
    const float4* W4 = reinterpret_cast<const float4*>(W);
    for (int idx = tid; idx < 128 * 32; idx += 128) {
        int o = idx >> 5, q = idx & 31;
        float4 w = W4[idx];
        *reinterpret_cast<float4*>(&Ws[o * WS + 4 * q]) = w;
    }
    __syncthreads();

    const int rowBase = blockIdx.x * 64;
    const float4* Wrow = reinterpret_cast<const float4*>(&Ws[tid * WS]);

    for (int pass = 0; pass < 16; ++pass) {
        const int r0 = rowBase + pass * 4;
        {
            int rr = tid >> 5, q = tid & 31;
            int row = r0 + rr;
            float4 v = make_float4(0.f, 0.f, 0.f, 0.f);
            if (row < N) v = reinterpret_cast<const float4*>(x + (size_t)row * D)[q];
            xs4[rr][q] = v;
        }
        __syncthreads();

        float acc0 = 0.f, acc1 = 0.f, acc2 = 0.f, acc3 = 0.f;
#pragma unroll
        for (int q = 0; q < 32; ++q) {
            float4 w = Wrow[q];
            float4 a0 = xs4[0][q], a1 = xs4[1][q], a2 = xs4[2][q], a3 = xs4[3][q];
            acc0 += w.x * a0.x + w.y * a0.y + w.z * a0.z + w.w * a0.w;
            acc1 += w.x * a1.x + w.y * a1.y + w.z * a1.z + w.w * a1.w;
            acc2 += w.x * a2.x + w.y * a2.y + w.z * a2.z + w.w * a2.w;
            acc3 += w.x * a3.x + w.y * a3.y + w.z * a3.z + w.w * a3.w;
        }
        if (r0 + 0 < N) h[(size_t)(r0 + 0) * D + tid] = acc0;
        if (r0 + 1 < N) h[(size_t)(r0 + 1) * D + tid] = acc1;
        if (r0 + 2 < N) h[(size_t)(r0 + 2) * D + tid] = acc2;
        if (r0 + 3 < N) h[(size_t)(r0 + 3) * D + tid] = acc3;
        __syncthreads();
    }
}

// ---------------------------------------------------------------------------
// Stage 2: out[rows[e]][:] += vals[e] * h[cols[e]][:]
// 32 threads per edge, each thread handles 4 consecutive floats (float4 gather,
// 4 scalar fp32 hardware atomics).
// ---------------------------------------------------------------------------
__global__ __launch_bounds__(256) void scatter_edges(const float* __restrict__ h,
                                                     const int* __restrict__ rows,
                                                     const int* __restrict__ cols,
                                                     const float* __restrict__ vals,
                                                     float* __restrict__ out,
                                                     int E) {
    int t = blockIdx.x * 256 + threadIdx.x;
    int e = t >> 5;
    if (e >= E) return;
    int q = t & 31;  // float4 index within the 128-wide row
    int r = rows[e];
    int c = cols[e];
    float v = vals[e];
    float4 m = reinterpret_cast<const float4*>(h + (size_t)c * D)[q];
    float* op = out + (size_t)r * D + q * 4;
    atomicAdd(op + 0, v * m.x);
    atomicAdd(op + 1, v * m.y);
    atomicAdd(op + 2, v * m.z);
    atomicAdd(op + 3, v * m.w);
}

extern "C" void kernel_launch(void* const* d_in, const int* in_sizes, int n_in,
                              void* d_out, int out_size, void* d_ws, size_t ws_size,
                              hipStream_t stream) {
    const float* x        = (const float*)d_in[0];
    const float* W        = (const float*)d_in[1];
    const int*   adj_rows = (const int*)d_in[2];
    const int*   adj_cols = (const int*)d_in[3];
    const float* adj_vals = (const float*)d_in[4];
    float* out = (float*)d_out;
    float* h   = (float*)d_ws;  // N*128 fp32 = 51.2 MB scratch

    const int N = in_sizes[0] / D;
    const int E = in_sizes[2];

    // d_out is poisoned by the harness; we accumulate with atomics -> zero it.
    hipMemsetAsync(d_out, 0, (size_t)out_size * sizeof(float), stream);

    const int gemmBlocks = (N + 63) / 64;
    gemm_xWt<<<gemmBlocks, 128, 0, stream>>>(x, W, h, N);

    const long long totalThreads = (long long)E * 32;
    const int scatterBlocks = (int)((totalThreads + 255) / 256);
    scatter_edges<<<scatterBlocks, 256, 0, stream>>>(h, adj_rows, adj_cols, adj_vals, out, E);
}

// Round 2
// 465.018 us; speedup vs baseline: 6.4150x; 6.4150x over previous
//
#include <hip/hip_runtime.h>

#define D 128  // D_IN == D_OUT == 128
#define SCAN_CHUNK 2048

// ---------------------------------------------------------------------------
// Stage 1: h = x * W^T.  64x64 tile per block, 256 threads, 4x4 register
// blocking. Tiles stored transposed [k][m] in LDS so inner loop is
// 2x ds_read_b128 + 16 FMA per k. LDS 64 KiB -> 2 blocks/CU.
// ---------------------------------------------------------------------------
__global__ __launch_bounds__(256) void gemm64(const float* __restrict__ x,
                                              const float* __restrict__ W,
                                              float* __restrict__ h, int N) {
    __shared__ float xs[128][64];  // [k][m]
    __shared__ float ws[128][64];  // [k][n]
    const int tid = threadIdx.x;
    const int m0 = blockIdx.x * 64;
    const int n0 = blockIdx.y * 64;

    // stage x tile: idx = q*64 + m  (q = float4 index 0..31, m = row 0..63)
    // -> ds_writes conflict-free (lanes write consecutive m), global reads
    //    cover full 64B lines per row.
    for (int idx = tid; idx < 2048; idx += 256) {
        int q = idx >> 6, m = idx & 63;
        int grow = m0 + m;
        float4 v = make_float4(0.f, 0.f, 0.f, 0.f);
        if (grow < N) v = *reinterpret_cast<const float4*>(x + (size_t)grow * D + q * 4);
        xs[q * 4 + 0][m] = v.x;
        xs[q * 4 + 1][m] = v.y;
        xs[q * 4 + 2][m] = v.z;
        xs[q * 4 + 3][m] = v.w;
    }
    for (int idx = tid; idx < 2048; idx += 256) {
        int q = idx >> 6, n = idx & 63;
        float4 v = *reinterpret_cast<const float4*>(W + (size_t)(n0 + n) * D + q * 4);
        ws[q * 4 + 0][n] = v.x;
        ws[q * 4 + 1][n] = v.y;
        ws[q * 4 + 2][n] = v.z;
        ws[q * 4 + 3][n] = v.w;
    }
    __syncthreads();

    const int tm = (tid & 15) * 4;
    const int tn = (tid >> 4) * 4;
    float acc[4][4] = {};
#pragma unroll 4
    for (int k = 0; k < 128; ++k) {
        float4 a4 = *reinterpret_cast<const float4*>(&xs[k][tm]);
        float4 b4 = *reinterpret_cast<const float4*>(&ws[k][tn]);
        float a[4] = {a4.x, a4.y, a4.z, a4.w};
        float b[4] = {b4.x, b4.y, b4.z, b4.w};
#pragma unroll
        for (int r = 0; r < 4; ++r)
#pragma unroll
            for (int c = 0; c < 4; ++c) acc[r][c] = fmaf(a[r], b[c], acc[r][c]);
    }
#pragma unroll
    for (int r = 0; r < 4; ++r) {
        int row = m0 + tm + r;
        if (row < N) {
            float4 o = make_float4(acc[r][0], acc[r][1], acc[r][2], acc[r][3]);
            *reinterpret_cast<float4*>(h + (size_t)row * D + n0 + tn) = o;
        }
    }
}

// ---------------------------------------------------------------------------
// CSR build: histogram -> two-level exclusive scan -> permutation scatter
// ---------------------------------------------------------------------------
__global__ __launch_bounds__(256) void hist_rows(const int* __restrict__ rows,
                                                 int* __restrict__ cnt, int E) {
    int e = blockIdx.x * 256 + threadIdx.x;
    if (e < E) atomicAdd(&cnt[rows[e]], 1);
}

__global__ __launch_bounds__(256) void scan_partial(const int* __restrict__ cnt,
                                                    int* __restrict__ blockSums, int N) {
    __shared__ int red[256];
    int b = blockIdx.x, t = threadIdx.x;
    int base = b * SCAN_CHUNK + t * 8;
    int s = 0;
#pragma unroll
    for (int j = 0; j < 8; ++j) {
        int idx = base + j;
        if (idx < N) s += cnt[idx];
    }
    red[t] = s;
    __syncthreads();
    for (int ofs = 128; ofs > 0; ofs >>= 1) {
        if (t < ofs) red[t] += red[t + ofs];
        __syncthreads();
    }
    if (t == 0) blockSums[b] = red[0];
}

__global__ void scan_block(int* __restrict__ blockSums, int* __restrict__ cnt_off,
                           int NB, int N) {
    if (threadIdx.x == 0 && blockIdx.x == 0) {
        int run = 0;
        for (int b = 0; b < NB; ++b) {
            int t = blockSums[b];
            blockSums[b] = run;
            run += t;
        }
        cnt_off[N] = run;  // == E
    }
}

__global__ __launch_bounds__(256) void scan_final(const int* __restrict__ blockSums,
                                                  int* __restrict__ cnt_off,  // in: counts, out: offsets
                                                  int* __restrict__ cursor, int N) {
    __shared__ int tsum[256];
    int b = blockIdx.x, t = threadIdx.x;
    int base = b * SCAN_CHUNK + t * 8;
    int v[8];
    int s = 0;
#pragma unroll
    for (int j = 0; j < 8; ++j) {
        int idx = base + j;
        v[j] = (idx < N) ? cnt_off[idx] : 0;
        s += v[j];
    }
    tsum[t] = s;
    __syncthreads();
    for (int ofs = 1; ofs < 256; ofs <<= 1) {
        int add = (t >= ofs) ? tsum[t - ofs] : 0;
        __syncthreads();
        tsum[t] += add;
        __syncthreads();
    }
    int run = blockSums[b] + tsum[t] - s;  // exclusive base for this thread
#pragma unroll
    for (int j = 0; j < 8; ++j) {
        int idx = base + j;
        if (idx < N) {
            cnt_off[idx] = run;
            cursor[idx]  = run;
            run += v[j];
        }
    }
}

__global__ __launch_bounds__(256) void build_perm(const int* __restrict__ rows,
                                                  int* __restrict__ cursor,
                                                  int* __restrict__ perm, int E) {
    int e = blockIdx.x * 256 + threadIdx.x;
    if (e < E) {
        int pos = atomicAdd(&cursor[rows[e]], 1);
        perm[pos] = e;
    }
}

// ---------------------------------------------------------------------------
// Stage 2 (CSR): one wave per output row; lane owns float2 of the 128-wide
// row. Edge (col,val) batch-loaded into registers, broadcast via __shfl.
// h[col] gathered as fully-coalesced 512B wave reads. NO fp32 atomics.
// ---------------------------------------------------------------------------
__global__ __launch_bounds__(256) void csr_gather(const float* __restrict__ h,
                                                  const int* __restrict__ offsets,
                                                  const int* __restrict__ perm,
                                                  const int* __restrict__ cols,
                                                  const float* __restrict__ vals,
                                                  float* __restrict__ out, int N) {
    const int row = blockIdx.x * 4 + (threadIdx.x >> 6);
    if (row >= N) return;
    const int lane = threadIdx.x & 63;
    const int beg = offsets[row];
    const int end = offsets[row + 1];
    float2 acc = make_float2(0.f, 0.f);

    for (int base = beg; base < end; base += 32) {
        const int rem = end - base;  // wave-uniform
        int c = 0;
        float v = 0.f;
        if (lane < 32 && lane < rem) {
            int e = perm[base + lane];
            c = cols[e];
            v = vals[e];
        }
#pragma unroll
        for (int j = 0; j < 32; ++j) {
            if (j >= rem) break;  // uniform early-exit, loop stays unrolled
            int cj   = __shfl(c, j);
            float vj = __shfl(v, j);
            const float2 m =
                *reinterpret_cast<const float2*>(h + (size_t)cj * D + lane * 2);
            acc.x = fmaf(vj, m.x, acc.x);
            acc.y = fmaf(vj, m.y, acc.y);
        }
    }
    *reinterpret_cast<float2*>(out + (size_t)row * D + lane * 2) = acc;
}

// ---------------------------------------------------------------------------
// Fallback (small workspace): atomic scatter, 32 threads/edge
// ---------------------------------------------------------------------------
__global__ __launch_bounds__(256) void scatter_edges(const float* __restrict__ h,
                                                     const int* __restrict__ rows,
                                                     const int* __restrict__ cols,
                                                     const float* __restrict__ vals,
                                                     float* __restrict__ out, int E) {
    int t = blockIdx.x * 256 + threadIdx.x;
    int e = t >> 5;
    if (e >= E) return;
    int q = t & 31;
    int r = rows[e];
    int c = cols[e];
    float v = vals[e];
    float4 m = reinterpret_cast<const float4*>(h + (size_t)c * D)[q];
    float* op = out + (size_t)r * D + q * 4;
    atomicAdd(op + 0, v * m.x);
    atomicAdd(op + 1, v * m.y);
    atomicAdd(op + 2, v * m.z);
    atomicAdd(op + 3, v * m.w);
}

extern "C" void kernel_launch(void* const* d_in, const int* in_sizes, int n_in,
                              void* d_out, int out_size, void* d_ws, size_t ws_size,
                              hipStream_t stream) {
    const float* x        = (const float*)d_in[0];
    const float* W        = (const float*)d_in[1];
    const int*   adj_rows = (const int*)d_in[2];
    const int*   adj_cols = (const int*)d_in[3];
    const float* adj_vals = (const float*)d_in[4];
    float* out = (float*)d_out;

    const int N = in_sizes[0] / D;
    const int E = in_sizes[2];
    const int NB = (N + SCAN_CHUNK - 1) / SCAN_CHUNK;

    // workspace carve-out (256B-aligned regions)
    size_t off = 0;
    auto carve = [&](size_t bytes) {
        void* p = (char*)d_ws + off;
        off += (bytes + 255) & ~(size_t)255;
        return p;
    };
    float* h        = (float*)carve((size_t)N * D * sizeof(float));
    int*   cnt_off  = (int*)carve((size_t)(N + 1) * sizeof(int));
    int*   cursor   = (int*)carve((size_t)N * sizeof(int));
    int*   blockSum = (int*)carve((size_t)NB * sizeof(int));
    int*   perm     = (int*)carve((size_t)E * sizeof(int));
    const bool fits = (off <= ws_size);

    // Stage 1: dense projection
    dim3 ggrid((N + 63) / 64, D / 64);
    gemm64<<<ggrid, 256, 0, stream>>>(x, W, h, N);

    if (fits) {
        // CSR build
        hipMemsetAsync(cnt_off, 0, (size_t)(N + 1) * sizeof(int), stream);
        hist_rows<<<(E + 255) / 256, 256, 0, stream>>>(adj_rows, cnt_off, E);
        scan_partial<<<NB, 256, 0, stream>>>(cnt_off, blockSum, N);
        scan_block<<<1, 64, 0, stream>>>(blockSum, cnt_off, NB, N);
        scan_final<<<NB, 256, 0, stream>>>(blockSum, cnt_off, cursor, N);
        build_perm<<<(E + 255) / 256, 256, 0, stream>>>(adj_rows, cursor, perm, E);
        // Segment-sum gather (writes every output row, no memset needed)
        csr_gather<<<(N + 3) / 4, 256, 0, stream>>>(h, cnt_off, perm, adj_cols,
                                                    adj_vals, out, N);
    } else {
        hipMemsetAsync(d_out, 0, (size_t)out_size * sizeof(float), stream);
        const long long tt = (long long)E * 32;
        scatter_edges<<<(int)((tt + 255) / 256), 256, 0, stream>>>(
            h, adj_rows, adj_cols, adj_vals, out, E);
    }
}

// Round 3
// 394.025 us; speedup vs baseline: 7.5709x; 1.1802x over previous
//
#include <hip/hip_runtime.h>

#define D 128  // D_IN == D_OUT == 128
#define SCAN_CHUNK 2048

typedef short bf16x8 __attribute__((ext_vector_type(8)));  // 8 bf16 = 4 VGPR
typedef float f32x4 __attribute__((ext_vector_type(4)));

__device__ inline unsigned short f2bf(float f) {  // RNE float->bf16
    unsigned u = __float_as_uint(f);
    unsigned r = u + 0x7FFFu + ((u >> 16) & 1u);
    return (unsigned short)(r >> 16);
}

// ---------------------------------------------------------------------------
// Cast fp32 -> bf16, 4 elements/thread, grid-stride
// ---------------------------------------------------------------------------
__global__ __launch_bounds__(256) void cast_bf16(const float* __restrict__ src,
                                                 unsigned short* __restrict__ dst,
                                                 long long n4) {
    long long i = (long long)blockIdx.x * 256 + threadIdx.x;
    const long long stride = (long long)gridDim.x * 256;
    for (; i < n4; i += stride) {
        float4 v = reinterpret_cast<const float4*>(src)[i];
        ushort4 o;
        o.x = f2bf(v.x); o.y = f2bf(v.y); o.z = f2bf(v.z); o.w = f2bf(v.w);
        reinterpret_cast<ushort4*>(dst)[i] = o;
    }
}

// ---------------------------------------------------------------------------
// CSR build: histogram -> two-level exclusive scan -> permutation scatter
// ---------------------------------------------------------------------------
__global__ __launch_bounds__(256) void hist_rows(const int* __restrict__ rows,
                                                 int* __restrict__ cnt, int E) {
    int e = blockIdx.x * 256 + threadIdx.x;
    if (e < E) atomicAdd(&cnt[rows[e]], 1);
}

__global__ __launch_bounds__(256) void scan_partial(const int* __restrict__ cnt,
                                                    int* __restrict__ blockSums, int N) {
    __shared__ int red[256];
    int b = blockIdx.x, t = threadIdx.x;
    int base = b * SCAN_CHUNK + t * 8;
    int s = 0;
#pragma unroll
    for (int j = 0; j < 8; ++j) {
        int idx = base + j;
        if (idx < N) s += cnt[idx];
    }
    red[t] = s;
    __syncthreads();
    for (int ofs = 128; ofs > 0; ofs >>= 1) {
        if (t < ofs) red[t] += red[t + ofs];
        __syncthreads();
    }
    if (t == 0) blockSums[b] = red[0];
}

__global__ void scan_block(int* __restrict__ blockSums, int* __restrict__ cnt_off,
                           int NB, int N) {
    if (threadIdx.x == 0 && blockIdx.x == 0) {
        int run = 0;
        for (int b = 0; b < NB; ++b) {
            int t = blockSums[b];
            blockSums[b] = run;
            run += t;
        }
        cnt_off[N] = run;  // == E
    }
}

__global__ __launch_bounds__(256) void scan_final(const int* __restrict__ blockSums,
                                                  int* __restrict__ cnt_off,
                                                  int* __restrict__ cursor, int N) {
    __shared__ int tsum[256];
    int b = blockIdx.x, t = threadIdx.x;
    int base = b * SCAN_CHUNK + t * 8;
    int v[8];
    int s = 0;
#pragma unroll
    for (int j = 0; j < 8; ++j) {
        int idx = base + j;
        v[j] = (idx < N) ? cnt_off[idx] : 0;
        s += v[j];
    }
    tsum[t] = s;
    __syncthreads();
    for (int ofs = 1; ofs < 256; ofs <<= 1) {
        int add = (t >= ofs) ? tsum[t - ofs] : 0;
        __syncthreads();
        tsum[t] += add;
        __syncthreads();
    }
    int run = blockSums[b] + tsum[t] - s;
#pragma unroll
    for (int j = 0; j < 8; ++j) {
        int idx = base + j;
        if (idx < N) {
            cnt_off[idx] = run;
            cursor[idx]  = run;
            run += v[j];
        }
    }
}

__global__ __launch_bounds__(256) void build_perm(const int* __restrict__ rows,
                                                  int* __restrict__ cursor,
                                                  int* __restrict__ perm, int E) {
    int e = blockIdx.x * 256 + threadIdx.x;
    if (e < E) {
        int pos = atomicAdd(&cursor[rows[e]], 1);
        perm[pos] = e;
    }
}

// ---------------------------------------------------------------------------
// Aggregation: y[row] = sum_e val_e * xb[col_e]  (xb bf16, acc fp32, y bf16)
// One wave per row; lane owns 2 columns (bf16x2 = 4B gather per lane).
// ---------------------------------------------------------------------------
__global__ __launch_bounds__(256) void csr_gather_bf16(
    const unsigned short* __restrict__ xb,
    const int* __restrict__ offsets,
    const int* __restrict__ perm,
    const int* __restrict__ cols,
    const float* __restrict__ vals,
    unsigned short* __restrict__ yb, int N) {
    const int row = blockIdx.x * 4 + (threadIdx.x >> 6);
    if (row >= N) return;
    const int lane = threadIdx.x & 63;
    const int beg = offsets[row], end = offsets[row + 1];
    float ax = 0.f, ay = 0.f;

    for (int base = beg; base < end; base += 32) {
        const int rem = end - base;  // wave-uniform
        int c = 0;
        float v = 0.f;
        if (lane < 32 && lane < rem) {
            int e = perm[base + lane];
            c = cols[e];
            v = vals[e];
        }
#pragma unroll
        for (int j = 0; j < 32; ++j) {
            if (j >= rem) break;  // uniform early exit keeps loop unrolled
            int cj   = __shfl(c, j);
            float vj = __shfl(v, j);
            unsigned u = *reinterpret_cast<const unsigned*>(xb + (size_t)cj * D + lane * 2);
            float lo = __uint_as_float(u << 16);
            float hi = __uint_as_float(u & 0xFFFF0000u);
            ax = fmaf(vj, lo, ax);
            ay = fmaf(vj, hi, ay);
        }
    }
    unsigned o = (unsigned)f2bf(ax) | ((unsigned)f2bf(ay) << 16);
    *reinterpret_cast<unsigned*>(yb + (size_t)row * D + lane * 2) = o;
}

// ---------------------------------------------------------------------------
// Projection: out = y * W^T via MFMA bf16 16x16x32.
// D = A*B: A[m][k] = y[m][k], B[k][n] = W[n][k].
// A-frag: lane l holds A[l&15][(l>>4)*8+j]  -> bf16x8 straight from y row.
// B-frag: lane l holds B[(l>>4)*8+j][l&15] = W[l&15][(l>>4)*8+j] -> from W row.
// C/D: col = lane&15, row = (lane>>4)*4 + reg  [m89-verified].
// 4 waves/block, wave = 16 rows x 128 cols = 8 tiles, K-loop of 4.
// ---------------------------------------------------------------------------
__global__ __launch_bounds__(256) void gemm_mfma(const unsigned short* __restrict__ yb,
                                                 const unsigned short* __restrict__ Wb,
                                                 float* __restrict__ out, int N) {
    const int wid  = threadIdx.x >> 6;
    const int lane = threadIdx.x & 63;
    const int m0   = blockIdx.x * 64 + wid * 16;
    const int r    = lane & 15;
    const int kg   = lane >> 4;  // 0..3
    const int arow = m0 + r;

    f32x4 acc[8] = {};
#pragma unroll
    for (int ks = 0; ks < 4; ++ks) {
        const int k0 = ks * 32 + kg * 8;
        bf16x8 a = {};
        if (arow < N) a = *reinterpret_cast<const bf16x8*>(yb + (size_t)arow * D + k0);
#pragma unroll
        for (int t = 0; t < 8; ++t) {
            bf16x8 b = *reinterpret_cast<const bf16x8*>(Wb + (size_t)(t * 16 + r) * D + k0);
            acc[t] = __builtin_amdgcn_mfma_f32_16x16x32_bf16(a, b, acc[t], 0, 0, 0);
        }
    }
#pragma unroll
    for (int t = 0; t < 8; ++t) {
#pragma unroll
        for (int i = 0; i < 4; ++i) {
            const int row = m0 + kg * 4 + i;
            if (row < N) out[(size_t)row * D + t * 16 + r] = acc[t][i];
        }
    }
}

// ---------------------------------------------------------------------------
// Fallback path (small ws): fp32 VALU GEMM + atomic scatter (R1 structure)
// ---------------------------------------------------------------------------
__global__ __launch_bounds__(256) void gemm64(const float* __restrict__ x,
                                              const float* __restrict__ W,
                                              float* __restrict__ h, int N) {
    __shared__ float xs[128][64];
    __shared__ float ws[128][64];
    const int tid = threadIdx.x;
    const int m0 = blockIdx.x * 64;
    const int n0 = blockIdx.y * 64;
    for (int idx = tid; idx < 2048; idx += 256) {
        int q = idx >> 6, m = idx & 63;
        int grow = m0 + m;
        float4 v = make_float4(0.f, 0.f, 0.f, 0.f);
        if (grow < N) v = *reinterpret_cast<const float4*>(x + (size_t)grow * D + q * 4);
        xs[q * 4 + 0][m] = v.x; xs[q * 4 + 1][m] = v.y;
        xs[q * 4 + 2][m] = v.z; xs[q * 4 + 3][m] = v.w;
    }
    for (int idx = tid; idx < 2048; idx += 256) {
        int q = idx >> 6, n = idx & 63;
        float4 v = *reinterpret_cast<const float4*>(W + (size_t)(n0 + n) * D + q * 4);
        ws[q * 4 + 0][n] = v.x; ws[q * 4 + 1][n] = v.y;
        ws[q * 4 + 2][n] = v.z; ws[q * 4 + 3][n] = v.w;
    }
    __syncthreads();
    const int tm = (tid & 15) * 4;
    const int tn = (tid >> 4) * 4;
    float acc[4][4] = {};
#pragma unroll 4
    for (int k = 0; k < 128; ++k) {
        float4 a4 = *reinterpret_cast<const float4*>(&xs[k][tm]);
        float4 b4 = *reinterpret_cast<const float4*>(&ws[k][tn]);
        float a[4] = {a4.x, a4.y, a4.z, a4.w};
        float b[4] = {b4.x, b4.y, b4.z, b4.w};
#pragma unroll
        for (int rr = 0; rr < 4; ++rr)
#pragma unroll
            for (int cc = 0; cc < 4; ++cc) acc[rr][cc] = fmaf(a[rr], b[cc], acc[rr][cc]);
    }
#pragma unroll
    for (int rr = 0; rr < 4; ++rr) {
        int row = m0 + tm + rr;
        if (row < N) {
            float4 o = make_float4(acc[rr][0], acc[rr][1], acc[rr][2], acc[rr][3]);
            *reinterpret_cast<float4*>(h + (size_t)row * D + n0 + tn) = o;
        }
    }
}

__global__ __launch_bounds__(256) void scatter_edges(const float* __restrict__ h,
                                                     const int* __restrict__ rows,
                                                     const int* __restrict__ cols,
                                                     const float* __restrict__ vals,
                                                     float* __restrict__ out, int E) {
    int t = blockIdx.x * 256 + threadIdx.x;
    int e = t >> 5;
    if (e >= E) return;
    int q = t & 31;
    int r = rows[e];
    int c = cols[e];
    float v = vals[e];
    float4 m = reinterpret_cast<const float4*>(h + (size_t)c * D)[q];
    float* op = out + (size_t)r * D + q * 4;
    atomicAdd(op + 0, v * m.x);
    atomicAdd(op + 1, v * m.y);
    atomicAdd(op + 2, v * m.z);
    atomicAdd(op + 3, v * m.w);
}

extern "C" void kernel_launch(void* const* d_in, const int* in_sizes, int n_in,
                              void* d_out, int out_size, void* d_ws, size_t ws_size,
                              hipStream_t stream) {
    const float* x        = (const float*)d_in[0];
    const float* W        = (const float*)d_in[1];
    const int*   adj_rows = (const int*)d_in[2];
    const int*   adj_cols = (const int*)d_in[3];
    const float* adj_vals = (const float*)d_in[4];
    float* out = (float*)d_out;

    const int N = in_sizes[0] / D;
    const int E = in_sizes[2];
    const int NB = (N + SCAN_CHUNK - 1) / SCAN_CHUNK;

    size_t off = 0;
    auto carve = [&](size_t bytes) {
        void* p = (char*)d_ws + off;
        off += (bytes + 255) & ~(size_t)255;
        return p;
    };
    unsigned short* xb       = (unsigned short*)carve((size_t)N * D * 2);   // 25.6 MB
    unsigned short* yb       = (unsigned short*)carve((size_t)N * D * 2);   // 25.6 MB
    unsigned short* Wb       = (unsigned short*)carve((size_t)D * D * 2);   // 32 KB
    int*   cnt_off  = (int*)carve((size_t)(N + 1) * sizeof(int));
    int*   cursor   = (int*)carve((size_t)N * sizeof(int));
    int*   blockSum = (int*)carve((size_t)NB * sizeof(int));
    int*   perm     = (int*)carve((size_t)E * sizeof(int));
    const bool fits = (off <= ws_size);

    if (fits) {
        // 1. casts
        cast_bf16<<<2048, 256, 0, stream>>>(x, xb, (long long)N * (D / 4));
        cast_bf16<<<16, 256, 0, stream>>>(W, Wb, (long long)D * (D / 4));
        // 2. CSR build
        hipMemsetAsync(cnt_off, 0, (size_t)(N + 1) * sizeof(int), stream);
        hist_rows<<<(E + 255) / 256, 256, 0, stream>>>(adj_rows, cnt_off, E);
        scan_partial<<<NB, 256, 0, stream>>>(cnt_off, blockSum, N);
        scan_block<<<1, 64, 0, stream>>>(blockSum, cnt_off, NB, N);
        scan_final<<<NB, 256, 0, stream>>>(blockSum, cnt_off, cursor, N);
        build_perm<<<(E + 255) / 256, 256, 0, stream>>>(adj_rows, cursor, perm, E);
        // 3. aggregate y = A * xb (bf16 out)
        csr_gather_bf16<<<(N + 3) / 4, 256, 0, stream>>>(xb, cnt_off, perm, adj_cols,
                                                         adj_vals, yb, N);
        // 4. project out = y * W^T (MFMA)
        gemm_mfma<<<(N + 63) / 64, 256, 0, stream>>>(yb, Wb, out, N);
    } else {
        // fallback: fp32 h + atomic scatter
        float* h = (float*)d_ws;
        hipMemsetAsync(d_out, 0, (size_t)out_size * sizeof(float), stream);
        dim3 ggrid((N + 63) / 64, D / 64);
        gemm64<<<ggrid, 256, 0, stream>>>(x, W, h, N);
        const long long tt = (long long)E * 32;
        scatter_edges<<<(int)((tt + 255) / 256), 256, 0, stream>>>(
            h, adj_rows, adj_cols, adj_vals, out, E);
    }
}

// Round 4
// 246.823 us; speedup vs baseline: 12.0860x; 1.5964x over previous
//
#include <hip/hip_runtime.h>

#define D 128          // D_IN == D_OUT == 128
#define RPB 512        // rows per bucket
#define RPB_SHIFT 9
#define HALF 256       // rows handled per csr_build block
#define BUCKMAX 256
#define TILE 8192      // edges per binning tile
#define SEGCAP 7168    // LDS pair capacity per csr_build block (56 KiB)

typedef short bf16x8 __attribute__((ext_vector_type(8)));
typedef float f32x4 __attribute__((ext_vector_type(4)));

__device__ inline unsigned short f2bf(float f) {  // RNE float->bf16
    unsigned u = __float_as_uint(f);
    unsigned r = u + 0x7FFFu + ((u >> 16) & 1u);
    return (unsigned short)(r >> 16);
}

// ---------------------------------------------------------------------------
// fp32 -> bf16 cast, 4 elements/thread, grid-stride
// ---------------------------------------------------------------------------
__global__ __launch_bounds__(256) void cast_bf16(const float* __restrict__ src,
                                                 unsigned short* __restrict__ dst,
                                                 long long n4) {
    long long i = (long long)blockIdx.x * 256 + threadIdx.x;
    const long long stride = (long long)gridDim.x * 256;
    for (; i < n4; i += stride) {
        float4 v = reinterpret_cast<const float4*>(src)[i];
        ushort4 o;
        o.x = f2bf(v.x); o.y = f2bf(v.y); o.z = f2bf(v.z); o.w = f2bf(v.w);
        reinterpret_cast<ushort4*>(dst)[i] = o;
    }
}

// ---------------------------------------------------------------------------
// Pass 0: exact per-bucket edge counts (bucket = row >> RPB_SHIFT)
// ---------------------------------------------------------------------------
__global__ __launch_bounds__(256) void bucket_hist(const int* __restrict__ rows,
                                                   int* __restrict__ bucketCnt,
                                                   int E, int NBUCK) {
    __shared__ int h[BUCKMAX];
    for (int i = threadIdx.x; i < BUCKMAX; i += 256) h[i] = 0;
    __syncthreads();
    const int t0 = blockIdx.x * TILE;
    const int tend = min(t0 + TILE, E);
    for (int i = t0 + threadIdx.x; i < tend; i += 256)
        atomicAdd(&h[rows[i] >> RPB_SHIFT], 1);
    __syncthreads();
    if (threadIdx.x < NBUCK && h[threadIdx.x])
        atomicAdd(&bucketCnt[threadIdx.x], h[threadIdx.x]);
}

// ---------------------------------------------------------------------------
// Tiny scan over NBUCK bucket counts -> exact packed bases; zero cursors.
// ---------------------------------------------------------------------------
__global__ void bucket_scan(const int* __restrict__ bucketCnt,
                            int* __restrict__ bucketBase,
                            int* __restrict__ bucketCur,
                            int* __restrict__ offsets, int NBUCK, int N) {
    if (threadIdx.x == 0) {
        int run = 0;
        for (int b = 0; b < NBUCK; ++b) {
            bucketBase[b] = run;
            run += bucketCnt[b];
        }
        bucketBase[NBUCK] = run;
        offsets[N] = run;  // == E
    }
    for (int i = threadIdx.x; i < NBUCK; i += blockDim.x) bucketCur[i] = 0;
}

// ---------------------------------------------------------------------------
// Pass 1: bin edges into bucket-major triplet arrays. Per-tile LDS histogram,
// ONE global atomic reservation per (tile,bucket), then writes land in the
// tile's private contiguous chunk -> lines assemble fully in a single L2.
// ---------------------------------------------------------------------------
__global__ __launch_bounds__(256) void binA(const int* __restrict__ rows,
                                            const int* __restrict__ cols,
                                            const float* __restrict__ vals,
                                            const int* __restrict__ bucketBase,
                                            int* __restrict__ bucketCur,
                                            int* __restrict__ rowb,
                                            int* __restrict__ colb,
                                            float* __restrict__ valb,
                                            int E, int NBUCK) {
    __shared__ int h[BUCKMAX];
    __shared__ int base[BUCKMAX];
    const int t0 = blockIdx.x * TILE;
    const int tend = min(t0 + TILE, E);
    for (int i = threadIdx.x; i < BUCKMAX; i += 256) h[i] = 0;
    __syncthreads();
    for (int i = t0 + threadIdx.x; i < tend; i += 256)
        atomicAdd(&h[rows[i] >> RPB_SHIFT], 1);
    __syncthreads();
    if (threadIdx.x < NBUCK) {
        int c = h[threadIdx.x];
        base[threadIdx.x] =
            c ? bucketBase[threadIdx.x] + atomicAdd(&bucketCur[threadIdx.x], c) : 0;
        h[threadIdx.x] = 0;  // reuse as local cursor
    }
    __syncthreads();
    for (int i = t0 + threadIdx.x; i < tend; i += 256) {
        int r = rows[i];
        int b = r >> RPB_SHIFT;
        int p = base[b] + atomicAdd(&h[b], 1);
        rowb[p] = r;
        colb[p] = cols[i];
        valb[p] = vals[i];
    }
}

// ---------------------------------------------------------------------------
// Pass 2: per 256-row half-bucket, build the CSR segment in LDS and write it
// out coalesced. Also emits per-row global offsets. Overflow (>SEGCAP) falls
// back to direct (correct, slower) global scatter.
// ---------------------------------------------------------------------------
__global__ __launch_bounds__(256) void csr_build(const int* __restrict__ rowb,
                                                 const int* __restrict__ colb,
                                                 const float* __restrict__ valb,
                                                 const int* __restrict__ bucketBase,
                                                 int* __restrict__ offsets,
                                                 uint2* __restrict__ pairs_g, int N) {
    __shared__ int hist[HALF];
    __shared__ int cur[HALF];
    __shared__ int tsum[256];
    __shared__ uint2 pr[SEGCAP];
    __shared__ int cntBelowSh;
    const int tid = threadIdx.x;
    const int buck = blockIdx.x >> 1, half = blockIdx.x & 1;
    const int row0 = buck * RPB + half * HALF;
    const int rbeg = bucketBase[buck], rend = bucketBase[buck + 1];

    hist[tid] = 0;
    if (tid == 0) cntBelowSh = 0;
    __syncthreads();

    // pass 1: histogram my 256 rows; count bucket edges below my range
    int below = 0;
    for (int i = rbeg + tid; i < rend; i += 256) {
        int d = rowb[i] - row0;
        if ((unsigned)d < (unsigned)HALF) atomicAdd(&hist[d], 1);
        else if (d < 0) ++below;
    }
    if (below) atomicAdd(&cntBelowSh, below);
    __syncthreads();

    // exclusive scan of hist[256]
    int part = hist[tid];
    tsum[tid] = part;
    __syncthreads();
    for (int ofs = 1; ofs < 256; ofs <<= 1) {
        int add = (tid >= ofs) ? tsum[tid - ofs] : 0;
        __syncthreads();
        tsum[tid] += add;
        __syncthreads();
    }
    const int excl = tsum[tid] - part;
    const int segcnt = tsum[255];
    const int segbase = rbeg + cntBelowSh;  // global CSR offset of row0

    cur[tid] = excl;
    const int grow = row0 + tid;
    if (grow < N) offsets[grow] = segbase + excl;
    __syncthreads();

    if (segcnt <= SEGCAP) {
        for (int i = rbeg + tid; i < rend; i += 256) {
            int r = rowb[i];
            int d = r - row0;
            if ((unsigned)d < (unsigned)HALF) {
                int p = atomicAdd(&cur[d], 1);
                pr[p] = make_uint2((unsigned)colb[i], __float_as_uint(valb[i]));
            }
        }
        __syncthreads();
        for (int p = tid; p < segcnt; p += 256) pairs_g[segbase + p] = pr[p];
    } else {  // overflow: direct scatter (correct for any data)
        for (int i = rbeg + tid; i < rend; i += 256) {
            int r = rowb[i];
            int d = r - row0;
            if ((unsigned)d < (unsigned)HALF) {
                int p = atomicAdd(&cur[d], 1);
                pairs_g[segbase + p] = make_uint2((unsigned)colb[i], __float_as_uint(valb[i]));
            }
        }
    }
}

// ---------------------------------------------------------------------------
// Aggregation: y[row] = sum val * xb[col]  (bf16 gather, fp32 acc, bf16 out)
// One wave per row; sorted (col,val) pairs read coalesced.
// ---------------------------------------------------------------------------
__global__ __launch_bounds__(256) void csr_gather_bf16(
    const unsigned short* __restrict__ xb,
    const int* __restrict__ offsets,
    const uint2* __restrict__ pairs,
    unsigned short* __restrict__ yb, int N) {
    const int row = blockIdx.x * 4 + (threadIdx.x >> 6);
    if (row >= N) return;
    const int lane = threadIdx.x & 63;
    const int beg = offsets[row], end = offsets[row + 1];
    float ax = 0.f, ay = 0.f;

    for (int base = beg; base < end; base += 32) {
        const int rem = end - base;  // wave-uniform
        int c = 0;
        float v = 0.f;
        if (lane < 32 && lane < rem) {
            uint2 e = pairs[base + lane];
            c = (int)e.x;
            v = __uint_as_float(e.y);
        }
#pragma unroll
        for (int j = 0; j < 32; ++j) {
            if (j >= rem) break;  // uniform early exit keeps loop unrolled
            int cj = __shfl(c, j);
            float vj = __shfl(v, j);
            unsigned u = *reinterpret_cast<const unsigned*>(xb + (size_t)cj * D + lane * 2);
            ax = fmaf(vj, __uint_as_float(u << 16), ax);
            ay = fmaf(vj, __uint_as_float(u & 0xFFFF0000u), ay);
        }
    }
    unsigned o = (unsigned)f2bf(ax) | ((unsigned)f2bf(ay) << 16);
    *reinterpret_cast<unsigned*>(yb + (size_t)row * D + lane * 2) = o;
}

// ---------------------------------------------------------------------------
// Projection: out = y * W^T via MFMA bf16 16x16x32 (layouts m89-verified).
// ---------------------------------------------------------------------------
__global__ __launch_bounds__(256) void gemm_mfma(const unsigned short* __restrict__ yb,
                                                 const unsigned short* __restrict__ Wb,
                                                 float* __restrict__ out, int N) {
    const int wid  = threadIdx.x >> 6;
    const int lane = threadIdx.x & 63;
    const int m0   = blockIdx.x * 64 + wid * 16;
    const int r    = lane & 15;
    const int kg   = lane >> 4;  // 0..3
    const int arow = m0 + r;

    f32x4 acc[8] = {};
#pragma unroll
    for (int ks = 0; ks < 4; ++ks) {
        const int k0 = ks * 32 + kg * 8;
        bf16x8 a = {};
        if (arow < N) a = *reinterpret_cast<const bf16x8*>(yb + (size_t)arow * D + k0);
#pragma unroll
        for (int t = 0; t < 8; ++t) {
            bf16x8 b = *reinterpret_cast<const bf16x8*>(Wb + (size_t)(t * 16 + r) * D + k0);
            acc[t] = __builtin_amdgcn_mfma_f32_16x16x32_bf16(a, b, acc[t], 0, 0, 0);
        }
    }
#pragma unroll
    for (int t = 0; t < 8; ++t) {
#pragma unroll
        for (int i = 0; i < 4; ++i) {
            const int row = m0 + kg * 4 + i;
            if (row < N) out[(size_t)row * D + t * 16 + r] = acc[t][i];
        }
    }
}

// ---------------------------------------------------------------------------
// Fallback path (tiny workspace): fp32 VALU GEMM + atomic scatter
// ---------------------------------------------------------------------------
__global__ __launch_bounds__(256) void gemm64(const float* __restrict__ x,
                                              const float* __restrict__ W,
                                              float* __restrict__ h, int N) {
    __shared__ float xs[128][64];
    __shared__ float ws[128][64];
    const int tid = threadIdx.x;
    const int m0 = blockIdx.x * 64;
    const int n0 = blockIdx.y * 64;
    for (int idx = tid; idx < 2048; idx += 256) {
        int q = idx >> 6, m = idx & 63;
        int grow = m0 + m;
        float4 v = make_float4(0.f, 0.f, 0.f, 0.f);
        if (grow < N) v = *reinterpret_cast<const float4*>(x + (size_t)grow * D + q * 4);
        xs[q * 4 + 0][m] = v.x; xs[q * 4 + 1][m] = v.y;
        xs[q * 4 + 2][m] = v.z; xs[q * 4 + 3][m] = v.w;
    }
    for (int idx = tid; idx < 2048; idx += 256) {
        int q = idx >> 6, n = idx & 63;
        float4 v = *reinterpret_cast<const float4*>(W + (size_t)(n0 + n) * D + q * 4);
        ws[q * 4 + 0][n] = v.x; ws[q * 4 + 1][n] = v.y;
        ws[q * 4 + 2][n] = v.z; ws[q * 4 + 3][n] = v.w;
    }
    __syncthreads();
    const int tm = (tid & 15) * 4;
    const int tn = (tid >> 4) * 4;
    float acc[4][4] = {};
#pragma unroll 4
    for (int k = 0; k < 128; ++k) {
        float4 a4 = *reinterpret_cast<const float4*>(&xs[k][tm]);
        float4 b4 = *reinterpret_cast<const float4*>(&ws[k][tn]);
        float a[4] = {a4.x, a4.y, a4.z, a4.w};
        float b[4] = {b4.x, b4.y, b4.z, b4.w};
#pragma unroll
        for (int rr = 0; rr < 4; ++rr)
#pragma unroll
            for (int cc = 0; cc < 4; ++cc) acc[rr][cc] = fmaf(a[rr], b[cc], acc[rr][cc]);
    }
#pragma unroll
    for (int rr = 0; rr < 4; ++rr) {
        int row = m0 + tm + rr;
        if (row < N) {
            float4 o = make_float4(acc[rr][0], acc[rr][1], acc[rr][2], acc[rr][3]);
            *reinterpret_cast<float4*>(h + (size_t)row * D + n0 + tn) = o;
        }
    }
}

__global__ __launch_bounds__(256) void scatter_edges(const float* __restrict__ h,
                                                     const int* __restrict__ rows,
                                                     const int* __restrict__ cols,
                                                     const float* __restrict__ vals,
                                                     float* __restrict__ out, int E) {
    int t = blockIdx.x * 256 + threadIdx.x;
    int e = t >> 5;
    if (e >= E) return;
    int q = t & 31;
    int r = rows[e];
    int c = cols[e];
    float v = vals[e];
    float4 m = reinterpret_cast<const float4*>(h + (size_t)c * D)[q];
    float* op = out + (size_t)r * D + q * 4;
    atomicAdd(op + 0, v * m.x);
    atomicAdd(op + 1, v * m.y);
    atomicAdd(op + 2, v * m.z);
    atomicAdd(op + 3, v * m.w);
}

extern "C" void kernel_launch(void* const* d_in, const int* in_sizes, int n_in,
                              void* d_out, int out_size, void* d_ws, size_t ws_size,
                              hipStream_t stream) {
    const float* x        = (const float*)d_in[0];
    const float* W        = (const float*)d_in[1];
    const int*   adj_rows = (const int*)d_in[2];
    const int*   adj_cols = (const int*)d_in[3];
    const float* adj_vals = (const float*)d_in[4];
    float* out = (float*)d_out;

    const int N = in_sizes[0] / D;
    const int E = in_sizes[2];
    const int NBUCK = (N + RPB - 1) / RPB;
    const int NT = (E + TILE - 1) / TILE;

    // ---- workspace carve (ws): bf16 buffers + offsets + counters ----
    size_t off = 0;
    auto carve = [&](size_t bytes) {
        void* p = (char*)d_ws + off;
        off += (bytes + 255) & ~(size_t)255;
        return p;
    };
    unsigned short* xb = (unsigned short*)carve((size_t)N * D * 2);  // 25.6 MB
    unsigned short* yb = (unsigned short*)carve((size_t)N * D * 2);  // 25.6 MB
    unsigned short* Wb = (unsigned short*)carve((size_t)D * D * 2);
    int* offsets   = (int*)carve((size_t)(N + 1) * sizeof(int));
    int* bucketCnt = (int*)carve((size_t)BUCKMAX * sizeof(int));
    int* bucketBase= (int*)carve((size_t)(BUCKMAX + 1) * sizeof(int));
    int* bucketCur = (int*)carve((size_t)BUCKMAX * sizeof(int));
    const size_t wsNeed = off;

    // ---- scratch carved from d_out (dead before gemm_mfma writes it) ----
    size_t doff = 0;
    auto carveOut = [&](size_t bytes) {
        void* p = (char*)d_out + doff;
        doff += (bytes + 255) & ~(size_t)255;
        return p;
    };
    int*   rowb    = (int*)carveOut((size_t)E * sizeof(int));
    int*   colb    = (int*)carveOut((size_t)E * sizeof(int));
    float* valb    = (float*)carveOut((size_t)E * sizeof(float));
    uint2* pairs_g = (uint2*)carveOut((size_t)E * sizeof(uint2));
    const size_t doutNeed = doff;

    const bool fits = (wsNeed <= ws_size) &&
                      (doutNeed <= (size_t)out_size * sizeof(float)) &&
                      (NBUCK <= BUCKMAX);

    if (fits) {
        // 1. bf16 casts
        cast_bf16<<<2048, 256, 0, stream>>>(x, xb, (long long)N * (D / 4));
        cast_bf16<<<16, 256, 0, stream>>>(W, Wb, (long long)D * (D / 4));
        // 2. CSR sort: hist -> bases -> bin -> segment assembly
        hipMemsetAsync(bucketCnt, 0, (size_t)BUCKMAX * sizeof(int), stream);
        bucket_hist<<<NT, 256, 0, stream>>>(adj_rows, bucketCnt, E, NBUCK);
        bucket_scan<<<1, 256, 0, stream>>>(bucketCnt, bucketBase, bucketCur,
                                           offsets, NBUCK, N);
        binA<<<NT, 256, 0, stream>>>(adj_rows, adj_cols, adj_vals, bucketBase,
                                     bucketCur, rowb, colb, valb, E, NBUCK);
        csr_build<<<NBUCK * 2, 256, 0, stream>>>(rowb, colb, valb, bucketBase,
                                                 offsets, pairs_g, N);
        // 3. aggregate y = A * xb
        csr_gather_bf16<<<(N + 3) / 4, 256, 0, stream>>>(xb, offsets, pairs_g, yb, N);
        // 4. project out = y * W^T (overwrites the d_out scratch)
        gemm_mfma<<<(N + 63) / 64, 256, 0, stream>>>(yb, Wb, out, N);
    } else {
        // fallback: fp32 h + atomic scatter
        float* h = (float*)d_ws;
        hipMemsetAsync(d_out, 0, (size_t)out_size * sizeof(float), stream);
        dim3 ggrid((N + 63) / 64, D / 64);
        gemm64<<<ggrid, 256, 0, stream>>>(x, W, h, N);
        const long long tt = (long long)E * 32;
        scatter_edges<<<(int)((tt + 255) / 256), 256, 0, stream>>>(
            h, adj_rows, adj_cols, adj_vals, out, E);
    }
}

// Round 5
// 194.768 us; speedup vs baseline: 15.3162x; 1.2673x over previous
//
#include <hip/hip_runtime.h>

#define D 128          // D_IN == D_OUT == 128
#define RPB 512        // rows per bucket
#define RPB_SHIFT 9
#define HALF 256       // rows handled per csr_build block
#define BUCKMAX 256
#define TILE 8192      // edges per binning tile
#define SEGCAP 7168    // LDS pair capacity per csr_build block (56 KiB)

typedef short bf16x8 __attribute__((ext_vector_type(8)));
typedef float f32x4 __attribute__((ext_vector_type(4)));

__device__ inline unsigned short f2bf(float f) {  // RNE float->bf16
    unsigned u = __float_as_uint(f);
    unsigned r = u + 0x7FFFu + ((u >> 16) & 1u);
    return (unsigned short)(r >> 16);
}

// ---------------------------------------------------------------------------
// fp32 -> bf16 cast, 4 elements/thread, grid-stride
// ---------------------------------------------------------------------------
__global__ __launch_bounds__(256) void cast_bf16(const float* __restrict__ src,
                                                 unsigned short* __restrict__ dst,
                                                 long long n4) {
    long long i = (long long)blockIdx.x * 256 + threadIdx.x;
    const long long stride = (long long)gridDim.x * 256;
    for (; i < n4; i += stride) {
        float4 v = reinterpret_cast<const float4*>(src)[i];
        ushort4 o;
        o.x = f2bf(v.x); o.y = f2bf(v.y); o.z = f2bf(v.z); o.w = f2bf(v.w);
        reinterpret_cast<ushort4*>(dst)[i] = o;
    }
}

// ---------------------------------------------------------------------------
// Pass 0: exact per-bucket edge counts (bucket = row >> RPB_SHIFT)
// ---------------------------------------------------------------------------
__global__ __launch_bounds__(256) void bucket_hist(const int* __restrict__ rows,
                                                   int* __restrict__ bucketCnt,
                                                   int E, int NBUCK) {
    __shared__ int h[BUCKMAX];
    for (int i = threadIdx.x; i < BUCKMAX; i += 256) h[i] = 0;
    __syncthreads();
    const int t0 = blockIdx.x * TILE;
    const int tend = min(t0 + TILE, E);
    for (int i = t0 + threadIdx.x; i < tend; i += 256)
        atomicAdd(&h[rows[i] >> RPB_SHIFT], 1);
    __syncthreads();
    if (threadIdx.x < NBUCK && h[threadIdx.x])
        atomicAdd(&bucketCnt[threadIdx.x], h[threadIdx.x]);
}

// ---------------------------------------------------------------------------
// Parallel exclusive scan over NBUCK (<=256) bucket counts; zero cursors.
// ---------------------------------------------------------------------------
__global__ __launch_bounds__(256) void bucket_scan(const int* __restrict__ bucketCnt,
                                                   int* __restrict__ bucketBase,
                                                   int* __restrict__ bucketCur,
                                                   int* __restrict__ offsets,
                                                   int NBUCK, int N) {
    __shared__ int t[256];
    const int tid = threadIdx.x;
    int v = (tid < NBUCK) ? bucketCnt[tid] : 0;
    t[tid] = v;
    __syncthreads();
    for (int ofs = 1; ofs < 256; ofs <<= 1) {
        int add = (tid >= ofs) ? t[tid - ofs] : 0;
        __syncthreads();
        t[tid] += add;
        __syncthreads();
    }
    if (tid < NBUCK) {
        bucketBase[tid] = t[tid] - v;  // exclusive
        bucketCur[tid] = 0;
    }
    if (tid == NBUCK - 1) {
        bucketBase[NBUCK] = t[tid];
        offsets[N] = t[tid];  // == E
    }
}

// ---------------------------------------------------------------------------
// Pass 1: bin edges into bucket-major triplet arrays. Per-tile LDS histogram,
// ONE global atomic reservation per (tile,bucket), then writes land in the
// tile's private contiguous chunk -> lines assemble fully in a single L2.
// ---------------------------------------------------------------------------
__global__ __launch_bounds__(256) void binA(const int* __restrict__ rows,
                                            const int* __restrict__ cols,
                                            const float* __restrict__ vals,
                                            const int* __restrict__ bucketBase,
                                            int* __restrict__ bucketCur,
                                            int* __restrict__ rowb,
                                            int* __restrict__ colb,
                                            float* __restrict__ valb,
                                            int E, int NBUCK) {
    __shared__ int h[BUCKMAX];
    __shared__ int base[BUCKMAX];
    const int t0 = blockIdx.x * TILE;
    const int tend = min(t0 + TILE, E);
    for (int i = threadIdx.x; i < BUCKMAX; i += 256) h[i] = 0;
    __syncthreads();
    for (int i = t0 + threadIdx.x; i < tend; i += 256)
        atomicAdd(&h[rows[i] >> RPB_SHIFT], 1);
    __syncthreads();
    if (threadIdx.x < NBUCK) {
        int c = h[threadIdx.x];
        base[threadIdx.x] =
            c ? bucketBase[threadIdx.x] + atomicAdd(&bucketCur[threadIdx.x], c) : 0;
        h[threadIdx.x] = 0;  // reuse as local cursor
    }
    __syncthreads();
    for (int i = t0 + threadIdx.x; i < tend; i += 256) {
        int r = rows[i];
        int b = r >> RPB_SHIFT;
        int p = base[b] + atomicAdd(&h[b], 1);
        rowb[p] = r;
        colb[p] = cols[i];
        valb[p] = vals[i];
    }
}

// ---------------------------------------------------------------------------
// Pass 2: per 256-row half-bucket, build the CSR segment in LDS and write it
// out coalesced. Also emits per-row global offsets. Overflow (>SEGCAP) falls
// back to direct (correct, slower) global scatter.
// ---------------------------------------------------------------------------
__global__ __launch_bounds__(256) void csr_build(const int* __restrict__ rowb,
                                                 const int* __restrict__ colb,
                                                 const float* __restrict__ valb,
                                                 const int* __restrict__ bucketBase,
                                                 int* __restrict__ offsets,
                                                 uint2* __restrict__ pairs_g, int N) {
    __shared__ int hist[HALF];
    __shared__ int cur[HALF];
    __shared__ int tsum[256];
    __shared__ uint2 pr[SEGCAP];
    __shared__ int cntBelowSh;
    const int tid = threadIdx.x;
    const int buck = blockIdx.x >> 1, half = blockIdx.x & 1;
    const int row0 = buck * RPB + half * HALF;
    const int rbeg = bucketBase[buck], rend = bucketBase[buck + 1];

    hist[tid] = 0;
    if (tid == 0) cntBelowSh = 0;
    __syncthreads();

    int below = 0;
    for (int i = rbeg + tid; i < rend; i += 256) {
        int d = rowb[i] - row0;
        if ((unsigned)d < (unsigned)HALF) atomicAdd(&hist[d], 1);
        else if (d < 0) ++below;
    }
    if (below) atomicAdd(&cntBelowSh, below);
    __syncthreads();

    int part = hist[tid];
    tsum[tid] = part;
    __syncthreads();
    for (int ofs = 1; ofs < 256; ofs <<= 1) {
        int add = (tid >= ofs) ? tsum[tid - ofs] : 0;
        __syncthreads();
        tsum[tid] += add;
        __syncthreads();
    }
    const int excl = tsum[tid] - part;
    const int segcnt = tsum[255];
    const int segbase = rbeg + cntBelowSh;

    cur[tid] = excl;
    const int grow = row0 + tid;
    if (grow < N) offsets[grow] = segbase + excl;
    __syncthreads();

    if (segcnt <= SEGCAP) {
        for (int i = rbeg + tid; i < rend; i += 256) {
            int r = rowb[i];
            int d = r - row0;
            if ((unsigned)d < (unsigned)HALF) {
                int p = atomicAdd(&cur[d], 1);
                pr[p] = make_uint2((unsigned)colb[i], __float_as_uint(valb[i]));
            }
        }
        __syncthreads();
        for (int p = tid; p < segcnt; p += 256) pairs_g[segbase + p] = pr[p];
    } else {
        for (int i = rbeg + tid; i < rend; i += 256) {
            int r = rowb[i];
            int d = r - row0;
            if ((unsigned)d < (unsigned)HALF) {
                int p = atomicAdd(&cur[d], 1);
                pairs_g[segbase + p] = make_uint2((unsigned)colb[i], __float_as_uint(valb[i]));
            }
        }
    }
}

// ---------------------------------------------------------------------------
// Aggregation: y[row] = sum val * xb[col]  (bf16 gather, fp32 acc, bf16 out)
// One wave per row. 64 pairs batch-loaded lane-parallel; inner loop is
// BRANCH-FREE groups of 8 {shfl, load, fma}: padding lanes carry c=0,v=0 so
// tail loads hit row 0 (hot) and tail FMAs add zero. 8 loads in flight.
// ---------------------------------------------------------------------------
__global__ __launch_bounds__(256) void csr_gather_bf16(
    const unsigned short* __restrict__ xb,
    const int* __restrict__ offsets,
    const uint2* __restrict__ pairs,
    unsigned short* __restrict__ yb, int N) {
    const int row = blockIdx.x * 4 + (threadIdx.x >> 6);
    if (row >= N) return;
    const int lane = threadIdx.x & 63;
    const int beg = offsets[row], end = offsets[row + 1];
    float ax = 0.f, ay = 0.f;

    for (int base = beg; base < end; base += 64) {
        const int rem = min(end - base, 64);  // wave-uniform
        uint2 e = make_uint2(0u, 0u);         // pad lanes: col 0, val 0
        if (lane < rem) e = pairs[base + lane];
        int c = (int)e.x;
        float v = __uint_as_float(e.y);

        for (int j0 = 0; j0 < rem; j0 += 8) {  // wave-uniform trip count
            int cj[8];
            float vj[8];
            unsigned u[8];
#pragma unroll
            for (int jj = 0; jj < 8; ++jj) {
                cj[jj] = __shfl(c, j0 + jj);
                vj[jj] = __shfl(v, j0 + jj);
            }
#pragma unroll
            for (int jj = 0; jj < 8; ++jj)
                u[jj] = *reinterpret_cast<const unsigned*>(
                    xb + (size_t)cj[jj] * D + lane * 2);
#pragma unroll
            for (int jj = 0; jj < 8; ++jj) {
                ax = fmaf(vj[jj], __uint_as_float(u[jj] << 16), ax);
                ay = fmaf(vj[jj], __uint_as_float(u[jj] & 0xFFFF0000u), ay);
            }
        }
    }
    unsigned o = (unsigned)f2bf(ax) | ((unsigned)f2bf(ay) << 16);
    *reinterpret_cast<unsigned*>(yb + (size_t)row * D + lane * 2) = o;
}

// ---------------------------------------------------------------------------
// Projection: out = y * W^T via MFMA bf16 16x16x32 (layouts m89-verified).
// ---------------------------------------------------------------------------
__global__ __launch_bounds__(256) void gemm_mfma(const unsigned short* __restrict__ yb,
                                                 const unsigned short* __restrict__ Wb,
                                                 float* __restrict__ out, int N) {
    const int wid  = threadIdx.x >> 6;
    const int lane = threadIdx.x & 63;
    const int m0   = blockIdx.x * 64 + wid * 16;
    const int r    = lane & 15;
    const int kg   = lane >> 4;  // 0..3
    const int arow = m0 + r;

    f32x4 acc[8] = {};
#pragma unroll
    for (int ks = 0; ks < 4; ++ks) {
        const int k0 = ks * 32 + kg * 8;
        bf16x8 a = {};
        if (arow < N) a = *reinterpret_cast<const bf16x8*>(yb + (size_t)arow * D + k0);
#pragma unroll
        for (int t = 0; t < 8; ++t) {
            bf16x8 b = *reinterpret_cast<const bf16x8*>(Wb + (size_t)(t * 16 + r) * D + k0);
            acc[t] = __builtin_amdgcn_mfma_f32_16x16x32_bf16(a, b, acc[t], 0, 0, 0);
        }
    }
#pragma unroll
    for (int t = 0; t < 8; ++t) {
#pragma unroll
        for (int i = 0; i < 4; ++i) {
            const int row = m0 + kg * 4 + i;
            if (row < N) out[(size_t)row * D + t * 16 + r] = acc[t][i];
        }
    }
}

// ---------------------------------------------------------------------------
// Fallback path (tiny workspace): fp32 VALU GEMM + atomic scatter
// ---------------------------------------------------------------------------
__global__ __launch_bounds__(256) void gemm64(const float* __restrict__ x,
                                              const float* __restrict__ W,
                                              float* __restrict__ h, int N) {
    __shared__ float xs[128][64];
    __shared__ float ws[128][64];
    const int tid = threadIdx.x;
    const int m0 = blockIdx.x * 64;
    const int n0 = blockIdx.y * 64;
    for (int idx = tid; idx < 2048; idx += 256) {
        int q = idx >> 6, m = idx & 63;
        int grow = m0 + m;
        float4 v = make_float4(0.f, 0.f, 0.f, 0.f);
        if (grow < N) v = *reinterpret_cast<const float4*>(x + (size_t)grow * D + q * 4);
        xs[q * 4 + 0][m] = v.x; xs[q * 4 + 1][m] = v.y;
        xs[q * 4 + 2][m] = v.z; xs[q * 4 + 3][m] = v.w;
    }
    for (int idx = tid; idx < 2048; idx += 256) {
        int q = idx >> 6, n = idx & 63;
        float4 v = *reinterpret_cast<const float4*>(W + (size_t)(n0 + n) * D + q * 4);
        ws[q * 4 + 0][n] = v.x; ws[q * 4 + 1][n] = v.y;
        ws[q * 4 + 2][n] = v.z; ws[q * 4 + 3][n] = v.w;
    }
    __syncthreads();
    const int tm = (tid & 15) * 4;
    const int tn = (tid >> 4) * 4;
    float acc[4][4] = {};
#pragma unroll 4
    for (int k = 0; k < 128; ++k) {
        float4 a4 = *reinterpret_cast<const float4*>(&xs[k][tm]);
        float4 b4 = *reinterpret_cast<const float4*>(&ws[k][tn]);
        float a[4] = {a4.x, a4.y, a4.z, a4.w};
        float b[4] = {b4.x, b4.y, b4.z, b4.w};
#pragma unroll
        for (int rr = 0; rr < 4; ++rr)
#pragma unroll
            for (int cc = 0; cc < 4; ++cc) acc[rr][cc] = fmaf(a[rr], b[cc], acc[rr][cc]);
    }
#pragma unroll
    for (int rr = 0; rr < 4; ++rr) {
        int row = m0 + tm + rr;
        if (row < N) {
            float4 o = make_float4(acc[rr][0], acc[rr][1], acc[rr][2], acc[rr][3]);
            *reinterpret_cast<float4*>(h + (size_t)row * D + n0 + tn) = o;
        }
    }
}

__global__ __launch_bounds__(256) void scatter_edges(const float* __restrict__ h,
                                                     const int* __restrict__ rows,
                                                     const int* __restrict__ cols,
                                                     const float* __restrict__ vals,
                                                     float* __restrict__ out, int E) {
    int t = blockIdx.x * 256 + threadIdx.x;
    int e = t >> 5;
    if (e >= E) return;
    int q = t & 31;
    int r = rows[e];
    int c = cols[e];
    float v = vals[e];
    float4 m = reinterpret_cast<const float4*>(h + (size_t)c * D)[q];
    float* op = out + (size_t)r * D + q * 4;
    atomicAdd(op + 0, v * m.x);
    atomicAdd(op + 1, v * m.y);
    atomicAdd(op + 2, v * m.z);
    atomicAdd(op + 3, v * m.w);
}

extern "C" void kernel_launch(void* const* d_in, const int* in_sizes, int n_in,
                              void* d_out, int out_size, void* d_ws, size_t ws_size,
                              hipStream_t stream) {
    const float* x        = (const float*)d_in[0];
    const float* W        = (const float*)d_in[1];
    const int*   adj_rows = (const int*)d_in[2];
    const int*   adj_cols = (const int*)d_in[3];
    const float* adj_vals = (const float*)d_in[4];
    float* out = (float*)d_out;

    const int N = in_sizes[0] / D;
    const int E = in_sizes[2];
    const int NBUCK = (N + RPB - 1) / RPB;
    const int NT = (E + TILE - 1) / TILE;

    size_t off = 0;
    auto carve = [&](size_t bytes) {
        void* p = (char*)d_ws + off;
        off += (bytes + 255) & ~(size_t)255;
        return p;
    };
    unsigned short* xb = (unsigned short*)carve((size_t)N * D * 2);  // 25.6 MB
    unsigned short* yb = (unsigned short*)carve((size_t)N * D * 2);  // 25.6 MB
    unsigned short* Wb = (unsigned short*)carve((size_t)D * D * 2);
    int* offsets   = (int*)carve((size_t)(N + 1) * sizeof(int));
    int* bucketCnt = (int*)carve((size_t)BUCKMAX * sizeof(int));
    int* bucketBase= (int*)carve((size_t)(BUCKMAX + 1) * sizeof(int));
    int* bucketCur = (int*)carve((size_t)BUCKMAX * sizeof(int));
    const size_t wsNeed = off;

    size_t doff = 0;
    auto carveOut = [&](size_t bytes) {
        void* p = (char*)d_out + doff;
        doff += (bytes + 255) & ~(size_t)255;
        return p;
    };
    int*   rowb    = (int*)carveOut((size_t)E * sizeof(int));
    int*   colb    = (int*)carveOut((size_t)E * sizeof(int));
    float* valb    = (float*)carveOut((size_t)E * sizeof(float));
    uint2* pairs_g = (uint2*)carveOut((size_t)E * sizeof(uint2));
    const size_t doutNeed = doff;

    const bool fits = (wsNeed <= ws_size) &&
                      (doutNeed <= (size_t)out_size * sizeof(float)) &&
                      (NBUCK <= BUCKMAX);

    if (fits) {
        cast_bf16<<<2048, 256, 0, stream>>>(x, xb, (long long)N * (D / 4));
        cast_bf16<<<16, 256, 0, stream>>>(W, Wb, (long long)D * (D / 4));
        hipMemsetAsync(bucketCnt, 0, (size_t)BUCKMAX * sizeof(int), stream);
        bucket_hist<<<NT, 256, 0, stream>>>(adj_rows, bucketCnt, E, NBUCK);
        bucket_scan<<<1, 256, 0, stream>>>(bucketCnt, bucketBase, bucketCur,
                                           offsets, NBUCK, N);
        binA<<<NT, 256, 0, stream>>>(adj_rows, adj_cols, adj_vals, bucketBase,
                                     bucketCur, rowb, colb, valb, E, NBUCK);
        csr_build<<<NBUCK * 2, 256, 0, stream>>>(rowb, colb, valb, bucketBase,
                                                 offsets, pairs_g, N);
        csr_gather_bf16<<<(N + 3) / 4, 256, 0, stream>>>(xb, offsets, pairs_g, yb, N);
        gemm_mfma<<<(N + 63) / 64, 256, 0, stream>>>(yb, Wb, out, N);
    } else {
        float* h = (float*)d_ws;
        hipMemsetAsync(d_out, 0, (size_t)out_size * sizeof(float), stream);
        dim3 ggrid((N + 63) / 64, D / 64);
        gemm64<<<ggrid, 256, 0, stream>>>(x, W, h, N);
        const long long tt = (long long)E * 32;
        scatter_edges<<<(int)((tt + 255) / 256), 256, 0, stream>>>(
            h, adj_rows, adj_cols, adj_vals, out, E);
    }
}